// Round 7
// baseline (106.471 us; speedup 1.0000x reference)
//
#include <hip/hip_runtime.h>
#include <math.h>

constexpr int NB = 1024;   // batch
constexpr int NT = 256;    // topic_size
constexpr int NE = 300;    // embedding_size
constexpr int NBATCH = 4;  // batches per k_main block (L2-traffic lever)

typedef float f32x2 __attribute__((ext_vector_type(2)));
typedef float f32x4 __attribute__((ext_vector_type(4)));

#if defined(__has_builtin)
#if __has_builtin(__builtin_amdgcn_exp2f)
#define EXP2F(x) __builtin_amdgcn_exp2f(x)
#else
#define EXP2F(x) exp2f(x)
#endif
#if __has_builtin(__builtin_amdgcn_logf)
#define LOG2F(x) __builtin_amdgcn_logf(x)
#else
#define LOG2F(x) log2f(x)
#endif
#else
#define EXP2F(x) exp2f(x)
#define LOG2F(x) log2f(x)
#endif

__device__ __forceinline__ float rdlane(float v, int l) {
  return __uint_as_float(__builtin_amdgcn_readlane(__float_as_uint(v), l));
}

// ===== packed f32 FMA helpers (VOP3P); all variants HW-proven (R2/R4/R5/R6,
// absmax 0.0).
__device__ __forceinline__ f32x2 pk_fma(f32x2 a, f32x2 b, f32x2 c) {
  f32x2 d;
  asm("v_pk_fma_f32 %0, %1, %2, %3" : "=v"(d) : "v"(a), "v"(b), "v"(c));
  return d;
}
__device__ __forceinline__ f32x2 pk_fma_alo(f32x2 a, f32x2 b, f32x2 c) {
  f32x2 d;
  asm("v_pk_fma_f32 %0, %1, %2, %3 op_sel:[0,0,0] op_sel_hi:[0,1,1]"
      : "=v"(d) : "v"(a), "v"(b), "v"(c));
  return d;
}
__device__ __forceinline__ f32x2 pk_fma_ahi(f32x2 a, f32x2 b, f32x2 c) {
  f32x2 d;
  asm("v_pk_fma_f32 %0, %1, %2, %3 op_sel:[1,0,0] op_sel_hi:[1,1,1]"
      : "=v"(d) : "v"(a), "v"(b), "v"(c));
  return d;
}
__device__ __forceinline__ f32x2 pk_fma_clo(f32x2 a, f32x2 b, f32x2 c) {
  f32x2 d;
  asm("v_pk_fma_f32 %0, %1, %2, %3 op_sel:[0,0,0] op_sel_hi:[1,1,0]"
      : "=v"(d) : "v"(a), "v"(b), "v"(c));
  return d;
}
__device__ __forceinline__ f32x2 pk_fma_chi(f32x2 a, f32x2 b, f32x2 c) {
  f32x2 d;
  asm("v_pk_fma_f32 %0, %1, %2, %3 op_sel:[0,0,1] op_sel_hi:[1,1,1]"
      : "=v"(d) : "v"(a), "v"(b), "v"(c));
  return d;
}

// ===== k_M: column blk of M. Mt[blk][t]=sum_e TE[e,t]*wf[blk,e].  (proven)
__global__ __launch_bounds__(1024) void k_M(const float* __restrict__ TE,
                                            const float* __restrict__ wf,
                                            float* __restrict__ Mt,
                                            float* __restrict__ Mrow) {
  __shared__ float red[4][NT];
  int tid = threadIdx.x;
  int q = __builtin_amdgcn_readfirstlane(tid >> 8);
  int c = tid & 255, lane = tid & 63, blk = blockIdx.x;

  const float* wrow = wf + blk * NE;
  float4 wa = *(const float4*)(wrow + 4 * lane);
  float4 wb = make_float4(0.f, 0.f, 0.f, 0.f);
  if (lane < 11) wb = *(const float4*)(wrow + 256 + 4 * lane);
  float acc = 0.f;
#pragma unroll
  for (int k = 0; k < 16; ++k) {  // chunks q+4k <= 63
    int ec = q + 4 * k;
    float wx = rdlane(wa.x, ec), wy = rdlane(wa.y, ec);
    float wz = rdlane(wa.z, ec), ww = rdlane(wa.w, ec);
    const float* tp = TE + 4 * ec * NT + c;
    acc = fmaf(tp[0], wx, acc);
    acc = fmaf(tp[NT], wy, acc);
    acc = fmaf(tp[2 * NT], wz, acc);
    acc = fmaf(tp[3 * NT], ww, acc);
  }
#pragma unroll
  for (int k = 16; k < 19; ++k) {  // chunks 64..74
    int ec = q + 4 * k;
    if (ec < 75) {  // wave-uniform
      int l = ec - 64;
      float wx = rdlane(wb.x, l), wy = rdlane(wb.y, l);
      float wz = rdlane(wb.z, l), ww = rdlane(wb.w, l);
      const float* tp = TE + 4 * ec * NT + c;
      acc = fmaf(tp[0], wx, acc);
      acc = fmaf(tp[NT], wy, acc);
      acc = fmaf(tp[2 * NT], wz, acc);
      acc = fmaf(tp[3 * NT], ww, acc);
    }
  }
  red[q][c] = acc;
  __syncthreads();
  if (q == 0) {
    float s = red[0][c] + red[1][c] + red[2][c] + red[3][c];
    Mt[blk * NT + c] = s;    // coalesced
    Mrow[c * NT + blk] = s;  // scattered, one-time
  }
}

// ===== k_G: row blk of G2=(M M^T)*log2e; Gd, Gof, u2.  (proven)
__global__ __launch_bounds__(1024) void k_G(const float* __restrict__ Mt,
                                            const float* __restrict__ Mrow,
                                            const float* __restrict__ bf,
                                            float* __restrict__ G2,
                                            float* __restrict__ u2,
                                            float* __restrict__ Gd,
                                            float* __restrict__ Gof) {
  __shared__ float red[4][NT];
  __shared__ float fin2[4][2];
  const float LOG2E = 1.4426950408889634f;
  int tid = threadIdx.x;
  int q = __builtin_amdgcn_readfirstlane(tid >> 8);
  int c = tid & 255, lane = tid & 63, wid = tid >> 6, blk = blockIdx.x;

  const float* mrowp = Mrow + blk * NT;
  float4 ma = *(const float4*)(mrowp + 4 * lane);
  float acc = 0.f;
  int c0 = q * 16;
#pragma unroll
  for (int k = 0; k < 16; ++k) {
    int fc = c0 + k;  // SGPR
    float mx = rdlane(ma.x, fc), my = rdlane(ma.y, fc);
    float mz = rdlane(ma.z, fc), mw = rdlane(ma.w, fc);
    const float* tp = Mt + 4 * fc * NT + c;
    acc = fmaf(tp[0], mx, acc);
    acc = fmaf(tp[NT], my, acc);
    acc = fmaf(tp[2 * NT], mz, acc);
    acc = fmaf(tp[3 * NT], mw, acc);
  }
  red[q][c] = acc;
  __syncthreads();
  if (q == 0) {
    float g = (red[0][c] + red[1][c] + red[2][c] + red[3][c]) * LOG2E;
    G2[blk * NT + c] = g;
    if (c == blk) Gd[blk] = g;
    float v = (c == blk) ? -3.0e38f : g;
#pragma unroll
    for (int off = 32; off > 0; off >>= 1) v = fmaxf(v, __shfl_down(v, off, 64));
    if (lane == 0) fin2[wid][0] = v;
    float p = mrowp[c] * bf[c];  // coalesced
#pragma unroll
    for (int off = 32; off > 0; off >>= 1) p += __shfl_down(p, off, 64);
    if (lane == 0) fin2[wid][1] = p;
  }
  __syncthreads();
  if (tid == 0) {
    float gof = fmaxf(fmaxf(fin2[0][0], fin2[1][0]), fmaxf(fin2[2][0], fin2[3][0]));
    Gof[blk] = fmaxf(gof, 0.f);
    u2[blk] = (fin2[0][1] + fin2[1][1] + fin2[2][1] + fin2[3][1]) * LOG2E;
  }
}

// ===== k_main: 512 threads (8 waves), NBATCH=4, grid 256 (1 block/CU).
// L2-traffic lever: one G2/Mrow dwordx4 feeds 16 exps (4 batches x 4 cols);
// total L2 traffic halves vs R6 (393 -> 197 MB).  Loop skeleton, op_sel
// pairings (even batch: alo/clo of pair b>>1; odd: ahi/chi), reduction
// k-order, and final shfl tree are R6-verbatim per batch -> bit-identical.
__global__ __launch_bounds__(512, 2) void k_main(
    const float* __restrict__ req, const float* __restrict__ wsdl,
    const float* __restrict__ Mrow, const float* __restrict__ G2,
    const float* __restrict__ u2, const float* __restrict__ Gd,
    const float* __restrict__ Gof, const float* __restrict__ bf,
    float* __restrict__ out) {
  __shared__ f32x4 Rs[NT];         // (r0,r1,r2,r3) per i                4 KB
  __shared__ f32x2 Us[NT];         // (u,u) per i                        2 KB
  __shared__ f32x4 Ws[NT];         // (w0,w1,w2,w3) per j                4 KB
  __shared__ f32x4 NLs[NT];        // (nL0,nL1,nL2,nL3) per j            4 KB
  __shared__ f32x4 QBq[NT];        // (Q0,Q1,Q2,Q3) per t                4 KB
  __shared__ f32x4 MHN[4][64];     // -mh per batch per col-quad         4 KB
  __shared__ f32x4 RRB[4][8][64];  // 8-way cross-wave partials         32 KB
  __shared__ float Avr[4 * NT];    // avr per (batch, col)               4 KB
  __shared__ float finU[4];
  __shared__ float fin[8][3];
  float* Avw = (float*)MHN;  // MHN dead after nL-reduce; reuse for avw

  int tid = threadIdx.x;
  int cq = tid & 63, q = tid >> 6;  // q == wave id; wave-uniform
  int c4 = cq * 4;
  int blk = blockIdx.x, b0 = blk * NBATCH, i0 = q * 32;
  int bsel = tid >> 8, col = tid & 255;

  // ---- stage loop-scalar arrays + up partials (waves 0-3) ----
  if (tid < NT) {
    float r0 = req[(b0 + 0) * NT + tid], r1 = req[(b0 + 1) * NT + tid];
    float r2 = req[(b0 + 2) * NT + tid], r3 = req[(b0 + 3) * NT + tid];
    float u = u2[tid];
    Rs[tid] = (f32x4){r0, r1, r2, r3};
    Us[tid] = (f32x2){u, u};
    Ws[tid] = (f32x4){wsdl[(b0 + 0) * NT + tid], wsdl[(b0 + 1) * NT + tid],
                      wsdl[(b0 + 2) * NT + tid], wsdl[(b0 + 3) * NT + tid]};
    float um = fmaxf(u, 0.f);
#pragma unroll
    for (int off = 32; off > 0; off >>= 1) um = fmaxf(um, __shfl_down(um, off, 64));
    if ((tid & 63) == 0) finU[tid >> 6] = um;
  }

  // ---- per-thread column-quad constants (dwordx4) ----
  f32x4 rcQ[NBATCH], wbQ[NBATCH];
#pragma unroll
  for (int b = 0; b < NBATCH; ++b) {
    rcQ[b] = *(const f32x4*)(req + (b0 + b) * NT + c4);
    wbQ[b] = *(const f32x4*)(wsdl + (b0 + b) * NT + c4);
  }
  f32x4 ucP = *(const f32x4*)(u2 + c4);
  f32x4 gdP = *(const f32x4*)(Gd + c4);
  f32x4 gofP = *(const f32x4*)(Gof + c4);

  __syncthreads();  // staging + finU ready
  float up = fmaxf(fmaxf(finU[0], finU[1]), fmaxf(finU[2], finU[3]));

  // Safe softmax upper bound per (batch, column) — proven formula.
  f32x2 wb01[NBATCH], wb23[NBATCH], rc01[NBATCH], rc23[NBATCH];
  f32x2 mh01[NBATCH], mh23[NBATCH];
#pragma unroll
  for (int b = 0; b < NBATCH; ++b) {
    f32x4 mhn;
    mhn.x = -fmaxf(rcQ[b].x * fmaf(wbQ[b].x, gdP.x, ucP.x), fmaf(wbQ[b].x, gofP.x, up));
    mhn.y = -fmaxf(rcQ[b].y * fmaf(wbQ[b].y, gdP.y, ucP.y), fmaf(wbQ[b].y, gofP.y, up));
    mhn.z = -fmaxf(rcQ[b].z * fmaf(wbQ[b].z, gdP.z, ucP.z), fmaf(wbQ[b].z, gofP.z, up));
    mhn.w = -fmaxf(rcQ[b].w * fmaf(wbQ[b].w, gdP.w, ucP.w), fmaf(wbQ[b].w, gofP.w, up));
    if (q == 0) MHN[b][cq] = mhn;  // covered by post-D barrier
    mh01[b] = (f32x2){mhn.x, mhn.y};
    mh23[b] = (f32x2){mhn.z, mhn.w};
    wb01[b] = (f32x2){wbQ[b].x, wbQ[b].y};
    wb23[b] = (f32x2){wbQ[b].z, wbQ[b].w};
    rc01[b] = (f32x2){rcQ[b].x, rcQ[b].y};
    rc23[b] = (f32x2){rcQ[b].z, rcQ[b].w};
  }
  f32x2 uc01 = (f32x2){ucP.x, ucP.y}, uc23 = (f32x2){ucP.z, ucP.w};

  // ---- Pass D: column denominators, 4 batches; i over wave's 32 rows ----
  f32x2 dA[NBATCH], dB[NBATCH];
#pragma unroll
  for (int b = 0; b < NBATCH; ++b) dA[b] = dB[b] = (f32x2){0.f, 0.f};
  {
    const float* gp = G2 + i0 * NT + c4;
    const char* rb_ = (const char*)(Rs + i0);
    const char* ub_ = (const char*)(Us + i0);
#pragma unroll 2
    for (int o = 0; o < 8; ++o) {
#pragma unroll
      for (int uu = 0; uu < 4; ++uu) {
        f32x4 gP = *(const f32x4*)(gp + uu * NT);
        f32x4 ru = *(const f32x4*)(rb_ + uu * 16);  // (r0,r1,r2,r3)
        f32x2 uP = *(const f32x2*)(ub_ + uu * 8);   // (u,u)
        f32x2 g01 = (f32x2){gP.x, gP.y}, g23 = (f32x2){gP.z, gP.w};
        f32x2 r01 = (f32x2){ru.x, ru.y}, r23 = (f32x2){ru.z, ru.w};
#pragma unroll
        for (int b = 0; b < NBATCH; ++b) {
          f32x2 rp = (b < 2) ? r01 : r23;
          f32x2 t01 = pk_fma(wb01[b], g01, uP);  // wb*g + u
          f32x2 t23 = pk_fma(wb23[b], g23, uP);
          f32x2 p01 = (b & 1) ? pk_fma_ahi(rp, t01, mh01[b])
                              : pk_fma_alo(rp, t01, mh01[b]);  // r_i*t - mh
          f32x2 p23 = (b & 1) ? pk_fma_ahi(rp, t23, mh23[b])
                              : pk_fma_alo(rp, t23, mh23[b]);
          dA[b] += (f32x2){EXP2F(p01.x), EXP2F(p01.y)};
          dB[b] += (f32x2){EXP2F(p23.x), EXP2F(p23.y)};
        }
      }
      gp += 4 * NT;
      rb_ += 64;
      ub_ += 32;
    }
  }
#pragma unroll
  for (int b = 0; b < NBATCH; ++b)
    RRB[b][q][cq] = (f32x4){dA[b].x, dA[b].y, dB[b].x, dB[b].y};
  __syncthreads();

  // ---- reduce D -> nL per (batch, col); 2 (b,col) pairs per thread ----
#pragma unroll
  for (int k2 = 0; k2 < 2; ++k2) {
    int b = 2 * k2 + bsel;
    const float* rb = (const float*)RRB + b * 2048;
    float den = rb[col];
#pragma unroll
    for (int k = 1; k < 8; ++k) den += rb[k * 256 + col];
    float nl = ((const float*)MHN)[b * 256 + col] - LOG2F(den);
    ((float*)(NLs + col))[b] = nl;
  }
  __syncthreads();

  // ---- Pass S: row sums of normalized att; rows c4..c4+3, 4 batches ----
  f32x2 SA[NBATCH], SB[NBATCH];
#pragma unroll
  for (int b = 0; b < NBATCH; ++b) SA[b] = SB[b] = (f32x2){0.f, 0.f};
  {
    const float* gp = G2 + i0 * NT + c4;  // G[c][j]=G[j][c] by symmetry
    const char* wb_ = (const char*)(Ws + i0);
    const char* nb_ = (const char*)(NLs + i0);
#pragma unroll 2
    for (int o = 0; o < 8; ++o) {
#pragma unroll
      for (int uu = 0; uu < 4; ++uu) {
        f32x4 gP = *(const f32x4*)(gp + uu * NT);
        f32x4 wq = *(const f32x4*)(wb_ + uu * 16);  // (w0,w1,w2,w3)
        f32x4 nq = *(const f32x4*)(nb_ + uu * 16);  // (nL0..nL3)
        f32x2 g01 = (f32x2){gP.x, gP.y}, g23 = (f32x2){gP.z, gP.w};
        f32x2 w01 = (f32x2){wq.x, wq.y}, w23 = (f32x2){wq.z, wq.w};
        f32x2 n01 = (f32x2){nq.x, nq.y}, n23 = (f32x2){nq.z, nq.w};
#pragma unroll
        for (int b = 0; b < NBATCH; ++b) {
          f32x2 wp = (b < 2) ? w01 : w23;
          f32x2 np = (b < 2) ? n01 : n23;
          f32x2 t01 = (b & 1) ? pk_fma_ahi(wp, g01, uc01)
                              : pk_fma_alo(wp, g01, uc01);  // w_j*g + uc
          f32x2 t23 = (b & 1) ? pk_fma_ahi(wp, g23, uc23)
                              : pk_fma_alo(wp, g23, uc23);
          f32x2 p01 = (b & 1) ? pk_fma_chi(rc01[b], t01, np)
                              : pk_fma_clo(rc01[b], t01, np);  // rc*t - L_j
          f32x2 p23 = (b & 1) ? pk_fma_chi(rc23[b], t23, np)
                              : pk_fma_clo(rc23[b], t23, np);
          SA[b] += (f32x2){EXP2F(p01.x), EXP2F(p01.y)};
          SB[b] += (f32x2){EXP2F(p23.x), EXP2F(p23.y)};
        }
      }
      gp += 4 * NT;
      wb_ += 64;
      nb_ += 64;
    }
  }
#pragma unroll
  for (int b = 0; b < NBATCH; ++b)
    RRB[b][q][cq] = (f32x4){SA[b].x, SA[b].y, SB[b].x, SB[b].y};
  __syncthreads();

  // ---- reduce S -> QBq = r_b * Srow_b per (batch, col) ----
#pragma unroll
  for (int k2 = 0; k2 < 2; ++k2) {
    int b = 2 * k2 + bsel;
    const float* rb = (const float*)RRB + b * 2048;
    float Sr = rb[col];
#pragma unroll
    for (int k = 1; k < 8; ++k) Sr += rb[k * 256 + col];
    float r = ((const float*)(Rs + col))[b];
    ((float*)(QBq + col))[b] = r * Sr;
  }
  __syncthreads();

  // ---- Pass B: ave_req = (r/T)@M + bf, ave_wsdl = (Q/T)@M + bf ----
  f32x2 aA[NBATCH], aB[NBATCH], yA[NBATCH], yB[NBATCH];
#pragma unroll
  for (int b = 0; b < NBATCH; ++b)
    aA[b] = aB[b] = yA[b] = yB[b] = (f32x2){0.f, 0.f};
  {
    const float* mp = Mrow + i0 * NT + c4;
    const char* rb_ = (const char*)(Rs + i0);
    const char* qb_ = (const char*)(QBq + i0);
#pragma unroll 2
    for (int o = 0; o < 8; ++o) {
#pragma unroll
      for (int uu = 0; uu < 4; ++uu) {
        f32x4 mkP = *(const f32x4*)(mp + uu * NT);
        f32x4 rq = *(const f32x4*)(rb_ + uu * 16);  // (r0..r3)
        f32x4 qq = *(const f32x4*)(qb_ + uu * 16);  // (Q0..Q3)
        f32x2 mk01 = (f32x2){mkP.x, mkP.y}, mk23 = (f32x2){mkP.z, mkP.w};
        f32x2 r01 = (f32x2){rq.x, rq.y}, r23 = (f32x2){rq.z, rq.w};
        f32x2 q01 = (f32x2){qq.x, qq.y}, q23 = (f32x2){qq.z, qq.w};
#pragma unroll
        for (int b = 0; b < NBATCH; ++b) {
          f32x2 rp = (b < 2) ? r01 : r23;
          f32x2 qp = (b < 2) ? q01 : q23;
          aA[b] = (b & 1) ? pk_fma_ahi(rp, mk01, aA[b])
                          : pk_fma_alo(rp, mk01, aA[b]);  // r_t*mk
          aB[b] = (b & 1) ? pk_fma_ahi(rp, mk23, aB[b])
                          : pk_fma_alo(rp, mk23, aB[b]);
          yA[b] = (b & 1) ? pk_fma_ahi(qp, mk01, yA[b])
                          : pk_fma_alo(qp, mk01, yA[b]);  // Q_t*mk
          yB[b] = (b & 1) ? pk_fma_ahi(qp, mk23, yB[b])
                          : pk_fma_alo(qp, mk23, yB[b]);
        }
      }
      mp += 4 * NT;
      rb_ += 64;
      qb_ += 64;
    }
  }
  const float invT = 1.0f / NT;
  float bfc = bf[col];
  // stage 1: a partials -> Avr
#pragma unroll
  for (int b = 0; b < NBATCH; ++b)
    RRB[b][q][cq] = (f32x4){aA[b].x, aA[b].y, aB[b].x, aB[b].y};
  __syncthreads();
#pragma unroll
  for (int k2 = 0; k2 < 2; ++k2) {
    int b = 2 * k2 + bsel;
    const float* rb = (const float*)RRB + b * 2048;
    float A = rb[col];
#pragma unroll
    for (int k = 1; k < 8; ++k) A += rb[k * 256 + col];
    Avr[b * 256 + col] = fmaf(A, invT, bfc);
  }
  __syncthreads();
  // stage 2: y partials -> Avw (reuses MHN space)
#pragma unroll
  for (int b = 0; b < NBATCH; ++b)
    RRB[b][q][cq] = (f32x4){yA[b].x, yA[b].y, yB[b].x, yB[b].y};
  __syncthreads();
#pragma unroll
  for (int k2 = 0; k2 < 2; ++k2) {
    int b = 2 * k2 + bsel;
    const float* rb = (const float*)RRB + b * 2048;
    float Y = rb[col];
#pragma unroll
    for (int k = 1; k < 8; ++k) Y += rb[k * 256 + col];
    Avw[b * 256 + col] = fmaf(Y, invT, bfc);
  }
  __syncthreads();

  // ---- final stats: two rounds, R6-verbatim tree per batch ----
#pragma unroll
  for (int p = 0; p < 2; ++p) {
    int b = 2 * p + bsel;
    float avr = Avr[b * 256 + col];
    float avw = Avw[b * 256 + col];
    float sn = avr * avw, sa = avr * avr, sc = avw * avw;
#pragma unroll
    for (int off = 32; off > 0; off >>= 1) {
      sn += __shfl_down(sn, off, 64);
      sa += __shfl_down(sa, off, 64);
      sc += __shfl_down(sc, off, 64);
    }
    if ((tid & 63) == 0) {
      int w = tid >> 6;  // 0-3: batch 2p, 4-7: batch 2p+1
      fin[w][0] = sn;
      fin[w][1] = sa;
      fin[w][2] = sc;
    }
    __syncthreads();
    if (tid < 2) {
      float N = 0.f, A = 0.f, C = 0.f;
#pragma unroll
      for (int w = 0; w < 4; ++w) {
        N += fin[tid * 4 + w][0];
        A += fin[tid * 4 + w][1];
        C += fin[tid * 4 + w][2];
      }
      out[b0 + 2 * p + tid] = N / fmaxf(sqrtf(A) * sqrtf(C), 1e-8f) * 3.0f;
    }
    __syncthreads();  // fin reused next round
  }
}

extern "C" void kernel_launch(void* const* d_in, const int* in_sizes, int n_in,
                              void* d_out, int out_size, void* d_ws, size_t ws_size,
                              hipStream_t stream) {
  const float* req  = (const float*)d_in[0];
  const float* wsdl = (const float*)d_in[1];
  const float* TE   = (const float*)d_in[2];
  const float* wf   = (const float*)d_in[3];
  const float* bf   = (const float*)d_in[4];
  float* out = (float*)d_out;

  // ws: [Mt | Mrow | G2 | u2 | Gd | Gof]
  float* Mt   = (float*)d_ws;
  float* Mrow = Mt + NT * NT;
  float* G2   = Mrow + NT * NT;
  float* u2   = G2 + NT * NT;
  float* Gd   = u2 + NT;
  float* Gof  = Gd + NT;

  k_M<<<NT, 1024, 0, stream>>>(TE, wf, Mt, Mrow);
  k_G<<<NT, 1024, 0, stream>>>(Mt, Mrow, bf, G2, u2, Gd, Gof);
  k_main<<<NB / NBATCH, 512, 0, stream>>>(req, wsdl, Mrow, G2, u2, Gd, Gof,
                                          bf, out);
}

// Round 8
// 93.158 us; speedup vs baseline: 1.1429x; 1.1429x over previous
//
#include <hip/hip_runtime.h>
#include <math.h>

constexpr int NB = 1024;   // batch
constexpr int NT = 256;    // topic_size
constexpr int NE = 300;    // embedding_size
constexpr int NBATCH = 2;  // batches per k_main block (R7 falsified 4: latency-bound)

typedef float f32x2 __attribute__((ext_vector_type(2)));
typedef float f32x4 __attribute__((ext_vector_type(4)));

#if defined(__has_builtin)
#if __has_builtin(__builtin_amdgcn_exp2f)
#define EXP2F(x) __builtin_amdgcn_exp2f(x)
#else
#define EXP2F(x) exp2f(x)
#endif
#if __has_builtin(__builtin_amdgcn_logf)
#define LOG2F(x) __builtin_amdgcn_logf(x)
#else
#define LOG2F(x) log2f(x)
#endif
#else
#define EXP2F(x) exp2f(x)
#define LOG2F(x) log2f(x)
#endif

__device__ __forceinline__ float rdlane(float v, int l) {
  return __uint_as_float(__builtin_amdgcn_readlane(__float_as_uint(v), l));
}

// ===== packed f32 FMA helpers (VOP3P); all variants HW-proven (R2/R4/R5/R6,
// absmax 0.0).
__device__ __forceinline__ f32x2 pk_fma(f32x2 a, f32x2 b, f32x2 c) {
  f32x2 d;
  asm("v_pk_fma_f32 %0, %1, %2, %3" : "=v"(d) : "v"(a), "v"(b), "v"(c));
  return d;
}
__device__ __forceinline__ f32x2 pk_fma_alo(f32x2 a, f32x2 b, f32x2 c) {
  f32x2 d;
  asm("v_pk_fma_f32 %0, %1, %2, %3 op_sel:[0,0,0] op_sel_hi:[0,1,1]"
      : "=v"(d) : "v"(a), "v"(b), "v"(c));
  return d;
}
__device__ __forceinline__ f32x2 pk_fma_ahi(f32x2 a, f32x2 b, f32x2 c) {
  f32x2 d;
  asm("v_pk_fma_f32 %0, %1, %2, %3 op_sel:[1,0,0] op_sel_hi:[1,1,1]"
      : "=v"(d) : "v"(a), "v"(b), "v"(c));
  return d;
}
__device__ __forceinline__ f32x2 pk_fma_clo(f32x2 a, f32x2 b, f32x2 c) {
  f32x2 d;
  asm("v_pk_fma_f32 %0, %1, %2, %3 op_sel:[0,0,0] op_sel_hi:[1,1,0]"
      : "=v"(d) : "v"(a), "v"(b), "v"(c));
  return d;
}
__device__ __forceinline__ f32x2 pk_fma_chi(f32x2 a, f32x2 b, f32x2 c) {
  f32x2 d;
  asm("v_pk_fma_f32 %0, %1, %2, %3 op_sel:[0,0,1] op_sel_hi:[1,1,1]"
      : "=v"(d) : "v"(a), "v"(b), "v"(c));
  return d;
}

// ===== k_M: column blk of M. Mt[blk][t]=sum_e TE[e,t]*wf[blk,e].  (proven)
__global__ __launch_bounds__(1024) void k_M(const float* __restrict__ TE,
                                            const float* __restrict__ wf,
                                            float* __restrict__ Mt,
                                            float* __restrict__ Mrow) {
  __shared__ float red[4][NT];
  int tid = threadIdx.x;
  int q = __builtin_amdgcn_readfirstlane(tid >> 8);
  int c = tid & 255, lane = tid & 63, blk = blockIdx.x;

  const float* wrow = wf + blk * NE;
  float4 wa = *(const float4*)(wrow + 4 * lane);
  float4 wb = make_float4(0.f, 0.f, 0.f, 0.f);
  if (lane < 11) wb = *(const float4*)(wrow + 256 + 4 * lane);
  float acc = 0.f;
#pragma unroll
  for (int k = 0; k < 16; ++k) {  // chunks q+4k <= 63
    int ec = q + 4 * k;
    float wx = rdlane(wa.x, ec), wy = rdlane(wa.y, ec);
    float wz = rdlane(wa.z, ec), ww = rdlane(wa.w, ec);
    const float* tp = TE + 4 * ec * NT + c;
    acc = fmaf(tp[0], wx, acc);
    acc = fmaf(tp[NT], wy, acc);
    acc = fmaf(tp[2 * NT], wz, acc);
    acc = fmaf(tp[3 * NT], ww, acc);
  }
#pragma unroll
  for (int k = 16; k < 19; ++k) {  // chunks 64..74
    int ec = q + 4 * k;
    if (ec < 75) {  // wave-uniform
      int l = ec - 64;
      float wx = rdlane(wb.x, l), wy = rdlane(wb.y, l);
      float wz = rdlane(wb.z, l), ww = rdlane(wb.w, l);
      const float* tp = TE + 4 * ec * NT + c;
      acc = fmaf(tp[0], wx, acc);
      acc = fmaf(tp[NT], wy, acc);
      acc = fmaf(tp[2 * NT], wz, acc);
      acc = fmaf(tp[3 * NT], ww, acc);
    }
  }
  red[q][c] = acc;
  __syncthreads();
  if (q == 0) {
    float s = red[0][c] + red[1][c] + red[2][c] + red[3][c];
    Mt[blk * NT + c] = s;    // coalesced
    Mrow[c * NT + blk] = s;  // scattered, one-time
  }
}

// ===== k_G: row blk of G2=(M M^T)*log2e; Gd, Gof, u2.  (proven)
__global__ __launch_bounds__(1024) void k_G(const float* __restrict__ Mt,
                                            const float* __restrict__ Mrow,
                                            const float* __restrict__ bf,
                                            float* __restrict__ G2,
                                            float* __restrict__ u2,
                                            float* __restrict__ Gd,
                                            float* __restrict__ Gof) {
  __shared__ float red[4][NT];
  __shared__ float fin2[4][2];
  const float LOG2E = 1.4426950408889634f;
  int tid = threadIdx.x;
  int q = __builtin_amdgcn_readfirstlane(tid >> 8);
  int c = tid & 255, lane = tid & 63, wid = tid >> 6, blk = blockIdx.x;

  const float* mrowp = Mrow + blk * NT;
  float4 ma = *(const float4*)(mrowp + 4 * lane);
  float acc = 0.f;
  int c0 = q * 16;
#pragma unroll
  for (int k = 0; k < 16; ++k) {
    int fc = c0 + k;  // SGPR
    float mx = rdlane(ma.x, fc), my = rdlane(ma.y, fc);
    float mz = rdlane(ma.z, fc), mw = rdlane(ma.w, fc);
    const float* tp = Mt + 4 * fc * NT + c;
    acc = fmaf(tp[0], mx, acc);
    acc = fmaf(tp[NT], my, acc);
    acc = fmaf(tp[2 * NT], mz, acc);
    acc = fmaf(tp[3 * NT], mw, acc);
  }
  red[q][c] = acc;
  __syncthreads();
  if (q == 0) {
    float g = (red[0][c] + red[1][c] + red[2][c] + red[3][c]) * LOG2E;
    G2[blk * NT + c] = g;
    if (c == blk) Gd[blk] = g;
    float v = (c == blk) ? -3.0e38f : g;
#pragma unroll
    for (int off = 32; off > 0; off >>= 1) v = fmaxf(v, __shfl_down(v, off, 64));
    if (lane == 0) fin2[wid][0] = v;
    float p = mrowp[c] * bf[c];  // coalesced
#pragma unroll
    for (int off = 32; off > 0; off >>= 1) p += __shfl_down(p, off, 64);
    if (lane == 0) fin2[wid][1] = p;
  }
  __syncthreads();
  if (tid == 0) {
    float gof = fmaxf(fmaxf(fin2[0][0], fin2[1][0]), fmaxf(fin2[2][0], fin2[3][0]));
    Gof[blk] = fmaxf(gof, 0.f);
    u2[blk] = (fin2[0][1] + fin2[1][1] + fin2[2][1] + fin2[3][1]) * LOG2E;
  }
}

// ===== k_main: R6 structure (512 thr, NBATCH=2, grid 512) + explicit 1-deep
// software pipeline in all three hot loops: next o-step's 4 G2/Mrow quads AND
// 4 LDS quads are register-double-buffered, issued BEFORE current compute.
// Breaks the post-barrier load convoy R6's stall profile implies (80% stall
// at 5-6us issue floor).  Math bit-identical to R6; only load timing moves.
// VGPR ~100-110, under the (512,4) 128-reg cap.
__global__ __launch_bounds__(512, 4) void k_main(
    const float* __restrict__ req, const float* __restrict__ wsdl,
    const float* __restrict__ Mrow, const float* __restrict__ G2,
    const float* __restrict__ u2, const float* __restrict__ Gd,
    const float* __restrict__ Gof, const float* __restrict__ bf,
    float* __restrict__ out) {
  __shared__ f32x4 sArr[NT];       // (r0_i, r1_i, u_i, u_i)          4 KB
  __shared__ f32x4 WL[NT];         // (w0_j, w1_j, nL0_j, nL1_j)      4 KB
  __shared__ f32x4 QB[NT];         // (r0_t, r1_t, Q0_t, Q1_t)        4 KB
  __shared__ f32x4 MHN[2][64];     // -mh per batch per column        2 KB
  __shared__ f32x4 RRB[4][8][64];  // 8-way cross-wave partials      32 KB
  __shared__ float finU[4];
  __shared__ float fin[8][3];

  int tid = threadIdx.x;
  int cq = tid & 63, q = tid >> 6;  // q == wave id; wave-uniform
  int c4 = cq * 4;
  int blk = blockIdx.x, b0 = blk * NBATCH, i0 = q * 32;

  // ---- stage loop-scalar arrays + up partials (waves 0-3) ----
  if (tid < NT) {
    float r0 = req[b0 * NT + tid], r1 = req[(b0 + 1) * NT + tid];
    float u = u2[tid];
    sArr[tid] = (f32x4){r0, r1, u, u};
    WL[tid] = (f32x4){wsdl[b0 * NT + tid], wsdl[(b0 + 1) * NT + tid], 0.f, 0.f};
    QB[tid] = (f32x4){r0, r1, 0.f, 0.f};
    float um = fmaxf(u, 0.f);
#pragma unroll
    for (int off = 32; off > 0; off >>= 1) um = fmaxf(um, __shfl_down(um, off, 64));
    if ((tid & 63) == 0) finU[tid >> 6] = um;
  }

  // ---- per-thread column-quad constants (dwordx4) ----
  f32x4 rc0P = *(const f32x4*)(req + b0 * NT + c4);
  f32x4 rc1P = *(const f32x4*)(req + (b0 + 1) * NT + c4);
  f32x4 wb0P = *(const f32x4*)(wsdl + b0 * NT + c4);
  f32x4 wb1P = *(const f32x4*)(wsdl + (b0 + 1) * NT + c4);
  f32x4 ucP = *(const f32x4*)(u2 + c4);
  f32x4 gdP = *(const f32x4*)(Gd + c4);
  f32x4 gofP = *(const f32x4*)(Gof + c4);

  __syncthreads();  // staging + finU ready
  float up = fmaxf(fmaxf(finU[0], finU[1]), fmaxf(finU[2], finU[3]));

  // Safe softmax upper bound per (batch, column) — proven formula.
  f32x4 mhn0, mhn1;
  mhn0.x = -fmaxf(rc0P.x * fmaf(wb0P.x, gdP.x, ucP.x), fmaf(wb0P.x, gofP.x, up));
  mhn0.y = -fmaxf(rc0P.y * fmaf(wb0P.y, gdP.y, ucP.y), fmaf(wb0P.y, gofP.y, up));
  mhn0.z = -fmaxf(rc0P.z * fmaf(wb0P.z, gdP.z, ucP.z), fmaf(wb0P.z, gofP.z, up));
  mhn0.w = -fmaxf(rc0P.w * fmaf(wb0P.w, gdP.w, ucP.w), fmaf(wb0P.w, gofP.w, up));
  mhn1.x = -fmaxf(rc1P.x * fmaf(wb1P.x, gdP.x, ucP.x), fmaf(wb1P.x, gofP.x, up));
  mhn1.y = -fmaxf(rc1P.y * fmaf(wb1P.y, gdP.y, ucP.y), fmaf(wb1P.y, gofP.y, up));
  mhn1.z = -fmaxf(rc1P.z * fmaf(wb1P.z, gdP.z, ucP.z), fmaf(wb1P.z, gofP.z, up));
  mhn1.w = -fmaxf(rc1P.w * fmaf(wb1P.w, gdP.w, ucP.w), fmaf(wb1P.w, gofP.w, up));
  if (q == 0) {  // covered by post-D barrier
    MHN[0][cq] = mhn0;
    MHN[1][cq] = mhn1;
  }

  f32x2 wb0_01 = (f32x2){wb0P.x, wb0P.y}, wb0_23 = (f32x2){wb0P.z, wb0P.w};
  f32x2 wb1_01 = (f32x2){wb1P.x, wb1P.y}, wb1_23 = (f32x2){wb1P.z, wb1P.w};
  f32x2 rc0_01 = (f32x2){rc0P.x, rc0P.y}, rc0_23 = (f32x2){rc0P.z, rc0P.w};
  f32x2 rc1_01 = (f32x2){rc1P.x, rc1P.y}, rc1_23 = (f32x2){rc1P.z, rc1P.w};
  f32x2 uc01 = (f32x2){ucP.x, ucP.y}, uc23 = (f32x2){ucP.z, ucP.w};
  f32x2 mhn0_01 = (f32x2){mhn0.x, mhn0.y}, mhn0_23 = (f32x2){mhn0.z, mhn0.w};
  f32x2 mhn1_01 = (f32x2){mhn1.x, mhn1.y}, mhn1_23 = (f32x2){mhn1.z, mhn1.w};

  // ---- Pass D: column denominators (software-pipelined) ----
  f32x2 d0a = (f32x2){0.f, 0.f}, d0b = d0a, d1a = d0a, d1b = d0a;
  {
    const float* gp = G2 + i0 * NT + c4;
    const char* sb = (const char*)(sArr + i0);
    f32x4 gcur[4], scur[4];
#pragma unroll
    for (int uu = 0; uu < 4; ++uu) {
      gcur[uu] = *(const f32x4*)(gp + uu * NT);
      scur[uu] = *(const f32x4*)(sb + uu * 16);
    }
#pragma unroll
    for (int o = 0; o < 8; ++o) {
      f32x4 gnxt[4], snxt[4];
      if (o < 7) {
        const float* gpn = gp + 4 * NT;
        const char* sbn = sb + 64;
#pragma unroll
        for (int uu = 0; uu < 4; ++uu) {
          gnxt[uu] = *(const f32x4*)(gpn + uu * NT);
          snxt[uu] = *(const f32x4*)(sbn + uu * 16);
        }
      }
#pragma unroll
      for (int uu = 0; uu < 4; ++uu) {
        f32x4 gP = gcur[uu];
        f32x4 su = scur[uu];  // (r0,r1,u,u) broadcast
        f32x2 su_lo = (f32x2){su.x, su.y};
        f32x2 uu_ = (f32x2){su.z, su.w};
        f32x2 g01 = (f32x2){gP.x, gP.y}, g23 = (f32x2){gP.z, gP.w};
        f32x2 t0_01 = pk_fma(wb0_01, g01, uu_);    // wb0*g + u
        f32x2 t0_23 = pk_fma(wb0_23, g23, uu_);
        f32x2 t1_01 = pk_fma(wb1_01, g01, uu_);
        f32x2 t1_23 = pk_fma(wb1_23, g23, uu_);
        f32x2 p0_01 = pk_fma_alo(su_lo, t0_01, mhn0_01);  // r0*t - mh0
        f32x2 p0_23 = pk_fma_alo(su_lo, t0_23, mhn0_23);
        f32x2 p1_01 = pk_fma_ahi(su_lo, t1_01, mhn1_01);  // r1*t - mh1
        f32x2 p1_23 = pk_fma_ahi(su_lo, t1_23, mhn1_23);
        d0a += (f32x2){EXP2F(p0_01.x), EXP2F(p0_01.y)};
        d0b += (f32x2){EXP2F(p0_23.x), EXP2F(p0_23.y)};
        d1a += (f32x2){EXP2F(p1_01.x), EXP2F(p1_01.y)};
        d1b += (f32x2){EXP2F(p1_23.x), EXP2F(p1_23.y)};
      }
      if (o < 7) {
#pragma unroll
        for (int uu = 0; uu < 4; ++uu) {
          gcur[uu] = gnxt[uu];
          scur[uu] = snxt[uu];
        }
      }
      gp += 4 * NT;
      sb += 64;
    }
  }
  RRB[0][q][cq] = (f32x4){d0a.x, d0a.y, d0b.x, d0b.y};
  RRB[1][q][cq] = (f32x4){d1a.x, d1a.y, d1b.x, d1b.y};
  __syncthreads();

  // ---- reduce D -> nL, batch-split over ALL 8 waves (bit-identical) ----
  {
    int bsel = tid >> 8, col = tid & 255;
    const float* rb = (const float*)RRB + bsel * 2048;
    float den = rb[col];
#pragma unroll
    for (int k = 1; k < 8; ++k) den += rb[k * 256 + col];
    float nl = ((const float*)MHN)[tid] - LOG2F(den);
    ((float*)(WL + col))[2 + bsel] = nl;
  }
  __syncthreads();

  // ---- Pass S: row sums of normalized att (software-pipelined) ----
  f32x2 S0a = (f32x2){0.f, 0.f}, S0b = S0a, S1a = S0a, S1b = S0a;
  {
    const float* gp = G2 + i0 * NT + c4;  // G[c][j]=G[j][c] by symmetry
    const char* wb_ = (const char*)(WL + i0);
    f32x4 gcur[4], wcur[4];
#pragma unroll
    for (int uu = 0; uu < 4; ++uu) {
      gcur[uu] = *(const f32x4*)(gp + uu * NT);
      wcur[uu] = *(const f32x4*)(wb_ + uu * 16);
    }
#pragma unroll
    for (int o = 0; o < 8; ++o) {
      f32x4 gnxt[4], wnxt[4];
      if (o < 7) {
        const float* gpn = gp + 4 * NT;
        const char* wbn = wb_ + 64;
#pragma unroll
        for (int uu = 0; uu < 4; ++uu) {
          gnxt[uu] = *(const f32x4*)(gpn + uu * NT);
          wnxt[uu] = *(const f32x4*)(wbn + uu * 16);
        }
      }
#pragma unroll
      for (int uu = 0; uu < 4; ++uu) {
        f32x4 gP = gcur[uu];
        f32x4 wl = wcur[uu];  // (w0,w1,nL0,nL1)
        f32x2 wl_lo = (f32x2){wl.x, wl.y};
        f32x2 wl_hi = (f32x2){wl.z, wl.w};
        f32x2 g01 = (f32x2){gP.x, gP.y}, g23 = (f32x2){gP.z, gP.w};
        f32x2 t0_01 = pk_fma_alo(wl_lo, g01, uc01);  // w0_j*g + uc
        f32x2 t0_23 = pk_fma_alo(wl_lo, g23, uc23);
        f32x2 t1_01 = pk_fma_ahi(wl_lo, g01, uc01);  // w1_j*g + uc
        f32x2 t1_23 = pk_fma_ahi(wl_lo, g23, uc23);
        f32x2 p0_01 = pk_fma_clo(rc0_01, t0_01, wl_hi);  // rc0*t - L0_j
        f32x2 p0_23 = pk_fma_clo(rc0_23, t0_23, wl_hi);
        f32x2 p1_01 = pk_fma_chi(rc1_01, t1_01, wl_hi);  // rc1*t - L1_j
        f32x2 p1_23 = pk_fma_chi(rc1_23, t1_23, wl_hi);
        S0a += (f32x2){EXP2F(p0_01.x), EXP2F(p0_01.y)};
        S0b += (f32x2){EXP2F(p0_23.x), EXP2F(p0_23.y)};
        S1a += (f32x2){EXP2F(p1_01.x), EXP2F(p1_01.y)};
        S1b += (f32x2){EXP2F(p1_23.x), EXP2F(p1_23.y)};
      }
      if (o < 7) {
#pragma unroll
        for (int uu = 0; uu < 4; ++uu) {
          gcur[uu] = gnxt[uu];
          wcur[uu] = wnxt[uu];
        }
      }
      gp += 4 * NT;
      wb_ += 64;
    }
  }
  RRB[0][q][cq] = (f32x4){S0a.x, S0a.y, S0b.x, S0b.y};
  RRB[1][q][cq] = (f32x4){S1a.x, S1a.y, S1b.x, S1b.y};
  __syncthreads();

  // ---- reduce S -> QB z/w, batch-split over ALL 8 waves ----
  {
    int bsel = tid >> 8, col = tid & 255;
    const float* rb = (const float*)RRB + bsel * 2048;
    float Sr = rb[col];
#pragma unroll
    for (int k = 1; k < 8; ++k) Sr += rb[k * 256 + col];
    float r = ((const float*)(sArr + col))[bsel];
    ((float*)(QB + col))[2 + bsel] = r * Sr;
  }
  __syncthreads();

  // ---- Pass B: ave vectors (software-pipelined) ----
  f32x2 a0_01 = (f32x2){0.f, 0.f}, a0_23 = a0_01, a1_01 = a0_01, a1_23 = a0_01;
  f32x2 y0_01 = a0_01, y0_23 = a0_01, y1_01 = a0_01, y1_23 = a0_01;
  {
    const float* mp = Mrow + i0 * NT + c4;
    const char* qb_ = (const char*)(QB + i0);
    f32x4 mcur[4], qcur[4];
#pragma unroll
    for (int uu = 0; uu < 4; ++uu) {
      mcur[uu] = *(const f32x4*)(mp + uu * NT);
      qcur[uu] = *(const f32x4*)(qb_ + uu * 16);
    }
#pragma unroll
    for (int o = 0; o < 8; ++o) {
      f32x4 mnxt[4], qnxt[4];
      if (o < 7) {
        const float* mpn = mp + 4 * NT;
        const char* qbn = qb_ + 64;
#pragma unroll
        for (int uu = 0; uu < 4; ++uu) {
          mnxt[uu] = *(const f32x4*)(mpn + uu * NT);
          qnxt[uu] = *(const f32x4*)(qbn + uu * 16);
        }
      }
#pragma unroll
      for (int uu = 0; uu < 4; ++uu) {
        f32x4 mkP = mcur[uu];
        f32x4 qb = qcur[uu];  // (r0,r1,Q0,Q1)
        f32x2 qb_lo = (f32x2){qb.x, qb.y};
        f32x2 qb_hi = (f32x2){qb.z, qb.w};
        f32x2 mk01 = (f32x2){mkP.x, mkP.y}, mk23 = (f32x2){mkP.z, mkP.w};
        a0_01 = pk_fma_alo(qb_lo, mk01, a0_01);  // r0_t*mk
        a0_23 = pk_fma_alo(qb_lo, mk23, a0_23);
        a1_01 = pk_fma_ahi(qb_lo, mk01, a1_01);  // r1_t*mk
        a1_23 = pk_fma_ahi(qb_lo, mk23, a1_23);
        y0_01 = pk_fma_alo(qb_hi, mk01, y0_01);  // Q0_t*mk
        y0_23 = pk_fma_alo(qb_hi, mk23, y0_23);
        y1_01 = pk_fma_ahi(qb_hi, mk01, y1_01);  // Q1_t*mk
        y1_23 = pk_fma_ahi(qb_hi, mk23, y1_23);
      }
      if (o < 7) {
#pragma unroll
        for (int uu = 0; uu < 4; ++uu) {
          mcur[uu] = mnxt[uu];
          qcur[uu] = qnxt[uu];
        }
      }
      mp += 4 * NT;
      qb_ += 64;
    }
  }
  RRB[0][q][cq] = (f32x4){a0_01.x, a0_01.y, a0_23.x, a0_23.y};
  RRB[1][q][cq] = (f32x4){a1_01.x, a1_01.y, a1_23.x, a1_23.y};
  RRB[2][q][cq] = (f32x4){y0_01.x, y0_01.y, y0_23.x, y0_23.y};
  RRB[3][q][cq] = (f32x4){y1_01.x, y1_01.y, y1_23.x, y1_23.y};
  __syncthreads();

  // ---- final stats, batch-split over ALL 8 waves (3 reduces/thread) ----
  {
    int bsel = tid >> 8, col = tid & 255;
    const float* rb = (const float*)RRB + bsel * 2048;
    float A = rb[col], Y = rb[4096 + col];  // a at 0/2048; y at 4096/6144
#pragma unroll
    for (int k = 1; k < 8; ++k) {
      A += rb[k * 256 + col];
      Y += rb[4096 + k * 256 + col];
    }
    float bfc = bf[col];
    const float invT = 1.0f / NT;
    float avr = fmaf(A, invT, bfc);
    float avw = fmaf(Y, invT, bfc);
    float sn = avr * avw, sa = avr * avr, sc = avw * avw;
#pragma unroll
    for (int off = 32; off > 0; off >>= 1) {
      sn += __shfl_down(sn, off, 64);
      sa += __shfl_down(sa, off, 64);
      sc += __shfl_down(sc, off, 64);
    }
    if ((tid & 63) == 0) {
      int w = tid >> 6;  // 0-3: batch0, 4-7: batch1
      fin[w][0] = sn;
      fin[w][1] = sa;
      fin[w][2] = sc;
    }
  }
  __syncthreads();
  if (tid < NBATCH) {
    int bb = tid;
    float N = 0.f, A = 0.f, C = 0.f;
#pragma unroll
    for (int w = 0; w < 4; ++w) {
      N += fin[bb * 4 + w][0];
      A += fin[bb * 4 + w][1];
      C += fin[bb * 4 + w][2];
    }
    out[b0 + bb] = N / fmaxf(sqrtf(A) * sqrtf(C), 1e-8f) * 3.0f;
  }
}

extern "C" void kernel_launch(void* const* d_in, const int* in_sizes, int n_in,
                              void* d_out, int out_size, void* d_ws, size_t ws_size,
                              hipStream_t stream) {
  const float* req  = (const float*)d_in[0];
  const float* wsdl = (const float*)d_in[1];
  const float* TE   = (const float*)d_in[2];
  const float* wf   = (const float*)d_in[3];
  const float* bf   = (const float*)d_in[4];
  float* out = (float*)d_out;

  // ws: [Mt | Mrow | G2 | u2 | Gd | Gof]
  float* Mt   = (float*)d_ws;
  float* Mrow = Mt + NT * NT;
  float* G2   = Mrow + NT * NT;
  float* u2   = G2 + NT * NT;
  float* Gd   = u2 + NT;
  float* Gof  = Gd + NT;

  k_M<<<NT, 1024, 0, stream>>>(TE, wf, Mt, Mrow);
  k_G<<<NT, 1024, 0, stream>>>(Mt, Mrow, bf, G2, u2, Gd, Gof);
  k_main<<<NB / NBATCH, 512, 0, stream>>>(req, wsdl, Mrow, G2, u2, Gd, Gof,
                                          bf, out);
}